// Round 4
// baseline (599.196 us; speedup 1.0000x reference)
//
#include <hip/hip_runtime.h>
#include <hip/hip_bf16.h>
#include <stdint.h>

typedef __attribute__((ext_vector_type(8))) short bf16x8;
typedef __attribute__((ext_vector_type(4))) float f32x4;
typedef __attribute__((ext_vector_type(2))) unsigned int u32x2;
typedef unsigned long long ull;

__device__ __forceinline__ void load_lds16(const void* g, void* l){
  __builtin_amdgcn_global_load_lds((const __attribute__((address_space(1))) void*)g,
                                   (__attribute__((address_space(3))) void*)l, 16, 0, 0);
}

__device__ __forceinline__ float bf2f(unsigned int u){
  union { unsigned int i; float f; } x; x.i = u << 16; return x.f;
}
__device__ __forceinline__ unsigned short f2bf(float f){
  __hip_bfloat16 h = __float2bfloat16(f);
  unsigned short u;
  __builtin_memcpy(&u, &h, 2);
  return u;
}

// ---------- conversions ----------
__global__ void cvt_x_kernel(const float4* __restrict__ in, ushort4* __restrict__ out, int n4){
  int i = blockIdx.x*256 + threadIdx.x;
  if (i < n4){
    float4 v = in[i];
    ushort4 o;
    o.x = f2bf(v.x); o.y = f2bf(v.y); o.z = f2bf(v.z); o.w = f2bf(v.w);
    out[i] = o;
  }
}

// Wt[n][k] = bf16(W[k][n]) for n < N, 0 for N <= n < Npad
__global__ void wtrans_kernel(const float* __restrict__ W, unsigned short* __restrict__ Wt,
                              int K, int N, int Npad){
  int idx = blockIdx.x*256 + threadIdx.x;
  if (idx >= Npad*K) return;
  int nn = idx / K, kk = idx - nn*K;
  float v = (nn < N) ? W[(size_t)kk*N + nn] : 0.f;
  Wt[idx] = f2bf(v);
}

// ---------- graph preprocessing ----------
__global__ void hist_kernel(const int* __restrict__ col, int E, int* __restrict__ deg){
  int i = blockIdx.x*256 + threadIdx.x;
  if (i < E) atomicAdd(&deg[col[i]], 1);
}

__global__ void dis_kernel(const int* __restrict__ d1, const int* __restrict__ d2,
                           float* __restrict__ s1, float* __restrict__ s2, int n){
  int i = blockIdx.x*256 + threadIdx.x;
  if (i < n){
    int a = d1[i]; s1[i] = (a > 0) ? (1.0f/sqrtf((float)a)) : 0.f;
    int b = d2[i]; s2[i] = (b > 0) ? (1.0f/sqrtf((float)b)) : 0.f;
  }
}

// scans run on PADDED degrees: pdeg = (deg+7)&~7  (8-edge multiples per node)
__global__ void scan1_kernel(const int* __restrict__ deg1, const int* __restrict__ deg2,
                             int* __restrict__ off1, int* __restrict__ off2,
                             int* __restrict__ bsum, int n){
  __shared__ int s[1024];
  int set = blockIdx.y;
  const int* deg = set ? deg2 : deg1;
  int* off = set ? off2 : off1;
  int tid = threadIdx.x;
  int i = blockIdx.x*1024 + tid;
  int v = (i < n) ? ((deg[i] + 7) & ~7) : 0;
  s[tid] = v;
  __syncthreads();
  for (int o = 1; o < 1024; o <<= 1){
    int t = (tid >= o) ? s[tid - o] : 0;
    __syncthreads();
    s[tid] += t;
    __syncthreads();
  }
  if (i < n) off[i] = s[tid];          // inclusive, chunk-local (fixed in pass 3)
  if (tid == 1023) bsum[set*64 + blockIdx.x] = s[1023];
}

__global__ void scan2_kernel(const int* __restrict__ bsum, int* __restrict__ bbase,
                             int nch, int* __restrict__ off1, int* __restrict__ off2, int n){
  int set = threadIdx.x;
  if (set < 2){
    int run = 0;
    for (int j = 0; j < nch; ++j){ bbase[set*64 + j] = run; run += bsum[set*64 + j]; }
    (set ? off2 : off1)[n] = run;      // total padded edge count
  }
}

__global__ void scan3_kernel(const int* __restrict__ deg1, const int* __restrict__ deg2,
                             int* __restrict__ off1, int* __restrict__ off2,
                             const int* __restrict__ bbase, int n){
  int set = blockIdx.y;
  const int* deg = set ? deg2 : deg1;
  int* off = set ? off2 : off1;
  int i = blockIdx.x*1024 + threadIdx.x;
  if (i < n){
    int e = off[i] + bbase[set*64 + blockIdx.x];
    off[i] = e - ((deg[i] + 7) & ~7);  // exclusive global padded prefix
  }
}

// pack {row, dis[row]} per edge, bucketed by destination col (pad slots stay {0,0})
__global__ void scatter_kernel(const int* __restrict__ ei, int E,
                               const int* __restrict__ off, int* __restrict__ cur,
                               const float* __restrict__ dis, int2* __restrict__ csr){
  int e = blockIdx.x*256 + threadIdx.x;
  if (e >= E) return;
  int r = ei[e], c = ei[E + e];
  int p = off[c] + atomicAdd(&cur[c], 1);
  int2 rec; rec.x = r; rec.y = __float_as_int(dis[r]);
  csr[p] = rec;
}

// ---------- GCN aggregation: out[c] = dis[c] * sum_e dis[r]*hw[r] + b ----------
// Pair-packed: lanes 0-31 handle even edges, 32-63 odd edges; each lane gathers
// an 8B (4-feature) chunk. 2-stage software pipeline over 4-pair (8-edge) batches;
// CSR is padded to 8-edge multiples with {row=0,d=0} so there are no tails.
__global__ __launch_bounds__(256) void conv_kernel(
    const int* __restrict__ off1, const ull* __restrict__ csr1, const float* __restrict__ dis1,
    const int* __restrict__ off2, const ull* __restrict__ csr2, const float* __restrict__ dis2,
    const u32x2* __restrict__ hwp,          // hw rows: 32 x u32x2 (=128 bf16) per node
    const float* __restrict__ bias, unsigned short* __restrict__ outR, int n)
{
  const int set = blockIdx.y;
  const int* __restrict__ off = set ? off2 : off1;
  const float* __restrict__ dis = set ? dis2 : dis1;
  const ull* __restrict__ csrq = set ? csr2 : csr1;
  const int col_ofs = set ? 128 : 0;

  int wv = blockIdx.x*4 + (threadIdx.x >> 6);
  if (wv >= n) return;
  const int l = threadIdx.x & 63;
  const int half = l >> 5, lf = l & 31;
  const int s = off[wv], e = off[wv+1];
  const int nb = (e - s) >> 3;               // 8-edge batches (exact, padded)
  const ull* cp = csrq + s + half;

  float ax = 0.f, ay = 0.f, az = 0.f, aw = 0.f;

  if (nb > 0){
    ull qa0,qa1,qa2,qa3, qb0,qb1,qb2,qb3;
    u32x2 va0,va1,va2,va3, vb0,vb1,vb2,vb3;
    float da0,da1,da2,da3, db0,db1,db2,db3;

#define LQ(q, base) \
    q##0 = __builtin_nontemporal_load(cp + (base));     \
    q##1 = __builtin_nontemporal_load(cp + (base) + 2); \
    q##2 = __builtin_nontemporal_load(cp + (base) + 4); \
    q##3 = __builtin_nontemporal_load(cp + (base) + 6);
#define GATH(v, q, d) \
    v##0 = hwp[(size_t)(unsigned)q##0 * 32 + lf]; \
    v##1 = hwp[(size_t)(unsigned)q##1 * 32 + lf]; \
    v##2 = hwp[(size_t)(unsigned)q##2 * 32 + lf]; \
    v##3 = hwp[(size_t)(unsigned)q##3 * 32 + lf]; \
    d##0 = __int_as_float((unsigned)(q##0 >> 32)); \
    d##1 = __int_as_float((unsigned)(q##1 >> 32)); \
    d##2 = __int_as_float((unsigned)(q##2 >> 32)); \
    d##3 = __int_as_float((unsigned)(q##3 >> 32));
#define FMA1(v, d) \
    ax = fmaf(d, bf2f(v.x & 0xffffu), ax); ay = fmaf(d, bf2f(v.x >> 16), ay); \
    az = fmaf(d, bf2f(v.y & 0xffffu), az); aw = fmaf(d, bf2f(v.y >> 16), aw);
#define FMAB(v, d) { FMA1(v##0, d##0) FMA1(v##1, d##1) FMA1(v##2, d##2) FMA1(v##3, d##3) }

    LQ(qa, 0)
    GATH(va, qa, da)
    LQ(qb, 8)
    int b = 0;
    while (b + 2 <= nb){
      // half 1: consume batch b, launch gathers for b+1, prefetch q(b+2)
      LQ(qa, (b + 2) * 8)          // speculative reads stay inside memset'd csr capacity
      GATH(vb, qb, db)
      FMAB(va, da)
      // half 2: consume batch b+1, launch gathers for b+2, prefetch q(b+3)
      LQ(qb, (b + 3) * 8)
      GATH(va, qa, da)             // if b+2 == nb this gathers row 0 / next node (valid), never used
      FMAB(vb, db)
      b += 2;
    }
    if (b < nb) FMAB(va, da)
#undef LQ
#undef GATH
#undef FMA1
#undef FMAB
  }

  // combine the two half-wave (edge-parity) partial sums
  ax += __shfl_xor(ax, 32, 64);
  ay += __shfl_xor(ay, 32, 64);
  az += __shfl_xor(az, 32, 64);
  aw += __shfl_xor(aw, 32, 64);

  const float dc = dis[wv];
  if (half == 0){
    float b0 = bias[lf*4 + 0], b1 = bias[lf*4 + 1];
    float b2 = bias[lf*4 + 2], b3 = bias[lf*4 + 3];
    ull ov = (ull)((unsigned)f2bf(fmaf(dc, ax, b0)) | ((unsigned)f2bf(fmaf(dc, ay, b1)) << 16))
           | ((ull)((unsigned)f2bf(fmaf(dc, az, b2)) | ((unsigned)f2bf(fmaf(dc, aw, b3)) << 16)) << 32);
    __builtin_nontemporal_store(ov, (ull*)&outR[(size_t)wv*256 + col_ofs + lf*4]);
  }
}

// ---------- bf16 MFMA GEMM, m97-style 2-barrier loop ----------
// A [M x K] bf16 row-major (lda), Bt = B^T stored [BN_total x K] bf16.
// EPI 0: plain bf16 store; EPI 1: +bias, relu, bf16 store;
// EPI 2: A = 3 slabs (h|R1|R2, lda=256 each), +bias, fused log_softmax, f32 store.
template<int FM, int FN, int WGM, int WGN, int EPI>
__global__ __launch_bounds__(256, 2) void gemm_kernel(
    const unsigned short* __restrict__ A0, const unsigned short* __restrict__ A1,
    const unsigned short* __restrict__ A2,
    const unsigned short* __restrict__ Bt, const float* __restrict__ bias,
    void* __restrict__ Cout, int M, int K, int lda, int ldc)
{
  constexpr int BM = WGM*FM*16;
  constexpr int BN = WGN*FN*16;
  constexpr int BK = 32;
  static_assert(BM == 128, "staging assumes BM==128");
  __shared__ unsigned short As[BM][BK];
  __shared__ unsigned short Bs[BN][BK];
  const int tid = threadIdx.x;
  const int w = tid >> 6, l = tid & 63;
  const int wr = w / WGN, wc = w % WGN;
  const int m0 = blockIdx.x*BM, n0 = blockIdx.y*BN;
  f32x4 acc[FM][FN] = {};
  const int nsteps = K / BK;
  for (int s = 0; s < nsteps; ++s){
    const int k0 = s*BK;
    const unsigned short* Asrc = A0;
    int kin = k0;
    if constexpr (EPI == 2){
      int slab = k0 >> 8;
      Asrc = (slab == 0) ? A0 : ((slab == 1) ? A1 : A2);
      kin = k0 & 255;
    }
    __syncthreads();
    #pragma unroll
    for (int j = 0; j < 2; ++j){           // A: 8KB = 2 x 4KB issues
      int idx = j*256 + tid;
      int row = idx >> 2, kq = idx & 3;
      int rg = m0 + row; rg = (rg < M) ? rg : (M - 1);
      load_lds16(Asrc + (size_t)rg*lda + kin + kq*8,
                 ((char*)&As[0][0]) + (size_t)(j*256 + w*64)*16);
    }
    #pragma unroll
    for (int j = 0; j < BN/64; ++j){       // Bt: [n][k] layout, same pattern as A
      int idx = j*256 + tid;
      int row = idx >> 2, kq = idx & 3;
      load_lds16(Bt + (size_t)(n0 + row)*K + k0 + kq*8,
                 ((char*)&Bs[0][0]) + (size_t)(j*256 + w*64)*16);
    }
    __syncthreads();
    bf16x8 af[FM], bfr[FN];
    const int kofs = (l >> 4)*8, l16 = l & 15;
    #pragma unroll
    for (int mi = 0; mi < FM; ++mi)
      af[mi] = *(const bf16x8*)&As[wr*FM*16 + mi*16 + l16][kofs];
    #pragma unroll
    for (int ni = 0; ni < FN; ++ni)
      bfr[ni] = *(const bf16x8*)&Bs[wc*FN*16 + ni*16 + l16][kofs];
    #pragma unroll
    for (int mi = 0; mi < FM; ++mi)
      #pragma unroll
      for (int ni = 0; ni < FN; ++ni)
        acc[mi][ni] = __builtin_amdgcn_mfma_f32_16x16x32_bf16(af[mi], bfr[ni], acc[mi][ni], 0, 0, 0);
  }
  const int lg = l >> 4, lc = l & 15;
  if constexpr (EPI == 2){
    float* O = (float*)Cout;
    #pragma unroll
    for (int mi = 0; mi < FM; ++mi){
      #pragma unroll
      for (int i = 0; i < 4; ++i){
        int row = m0 + wr*FM*16 + mi*16 + lg*4 + i;
        float v[FN];
        float mx = -1e30f;
        #pragma unroll
        for (int ni = 0; ni < FN; ++ni){
          int col = ni*16 + lc;                       // WGN==1, n0==0
          v[ni] = acc[mi][ni][i] + ((col < 40) ? bias[col] : 0.f);
          if (col < 40) mx = fmaxf(mx, v[ni]);
        }
        #pragma unroll
        for (int d = 1; d < 16; d <<= 1) mx = fmaxf(mx, __shfl_xor(mx, d, 64));
        float se = 0.f;
        #pragma unroll
        for (int ni = 0; ni < FN; ++ni){
          int col = ni*16 + lc;
          if (col < 40) se += expf(v[ni] - mx);
        }
        #pragma unroll
        for (int d = 1; d < 16; d <<= 1) se += __shfl_xor(se, d, 64);
        float lse = logf(se);
        if (row < M){
          #pragma unroll
          for (int ni = 0; ni < FN; ++ni){
            int col = ni*16 + lc;
            if (col < 40) O[(size_t)row*40 + col] = v[ni] - mx - lse;
          }
        }
      }
    }
  } else {
    unsigned short* C = (unsigned short*)Cout;
    #pragma unroll
    for (int mi = 0; mi < FM; ++mi){
      #pragma unroll
      for (int i = 0; i < 4; ++i){
        int row = m0 + wr*FM*16 + mi*16 + lg*4 + i;
        if (row >= M) continue;
        #pragma unroll
        for (int ni = 0; ni < FN; ++ni){
          int col = n0 + wc*FN*16 + ni*16 + lc;
          float vv = acc[mi][ni][i];
          if constexpr (EPI == 1){ vv += bias[col]; vv = fmaxf(vv, 0.f); }
          C[(size_t)row*ldc + col] = f2bf(vv);
        }
      }
    }
  }
}

extern "C" void kernel_launch(void* const* d_in, const int* in_sizes, int n_in,
                              void* d_out, int out_size, void* d_ws, size_t ws_size,
                              hipStream_t stream)
{
  (void)n_in; (void)out_size;
  const float* x      = (const float*)d_in[0];
  const int*   ei1    = (const int*)d_in[1];
  const int*   ei2    = (const int*)d_in[2];
  const float* W_lin1 = (const float*)d_in[3];
  const float* b_lin1 = (const float*)d_in[4];
  const float* W_c1   = (const float*)d_in[5];
  const float* b_c1   = (const float*)d_in[6];
  const float* W_c2   = (const float*)d_in[7];
  const float* b_c2   = (const float*)d_in[8];
  const float* W_lin2 = (const float*)d_in[9];
  const float* b_lin2 = (const float*)d_in[10];

  const int N  = in_sizes[0] / 512;
  const int E1 = in_sizes[1] / 2;
  const int E2 = in_sizes[2] / 2;

  char* base = (char*)d_ws;
  size_t off = 0;
  auto alloc = [&](size_t bytes) -> char* {
    off = (off + 255) & ~(size_t)255;
    char* r = base + off;
    off += bytes;
    return r;
  };
  // padded-CSR capacities (pad <= 7 per node, + speculative-prefetch slack)
  const size_t cap1 = (size_t)E1 + 8*(size_t)N + 64;
  const size_t cap2 = (size_t)E2 + 8*(size_t)N + 64;

  unsigned short* xb   = (unsigned short*)alloc((size_t)N*512*2);  // reused as CSR after GEMM1
  unsigned short* h    = (unsigned short*)alloc((size_t)N*256*2);
  unsigned short* hw   = (unsigned short*)alloc((size_t)N*128*2);  // hw1 then reused as hw2
  unsigned short* R1   = (unsigned short*)alloc((size_t)N*256*2);
  unsigned short* R2   = (unsigned short*)alloc((size_t)N*256*2);
  unsigned short* Wt1  = (unsigned short*)alloc((size_t)256*512*2);
  unsigned short* Wtc1 = (unsigned short*)alloc((size_t)128*256*2);
  unsigned short* Wtc2 = (unsigned short*)alloc((size_t)128*256*2);
  unsigned short* Wtf  = (unsigned short*)alloc((size_t)64*768*2); // W_lin2^T padded to 64 cols
  int* degblk = (int*)alloc((size_t)4*N*4);
  int* deg1 = degblk, *deg2 = degblk + N, *cur1 = degblk + 2*N, *cur2 = degblk + 3*N;
  float* dis1 = (float*)alloc((size_t)N*4);
  float* dis2 = (float*)alloc((size_t)N*4);
  int* off1 = (int*)alloc((size_t)(N+1)*4);
  int* off2 = (int*)alloc((size_t)(N+1)*4);
  int* bsum  = (int*)alloc(128*4);
  int* bbase = (int*)alloc(128*4);
  // CSR aliases the xb slab (xb is dead after GEMM1; 51.2MB >= 26MB needed)
  ull* csr1 = (ull*)xb;
  ull* csr2 = csr1 + cap1;
  if (off > ws_size) return;   // workspace insufficient -> visible validation failure

  int mt = (N + 127)/128;
  int cb = (N + 3)/4;

  // --- dense front: x->bf16, weight transposes, GEMM1 (uses xb before CSR aliases it) ---
  cvt_x_kernel<<<(N*512/4 + 255)/256, 256, 0, stream>>>((const float4*)x, (ushort4*)xb, N*512/4);
  wtrans_kernel<<<(256*512 + 255)/256, 256, 0, stream>>>(W_lin1, Wt1, 512, 256, 256);
  wtrans_kernel<<<(128*256 + 255)/256, 256, 0, stream>>>(W_c1, Wtc1, 256, 128, 128);
  wtrans_kernel<<<(128*256 + 255)/256, 256, 0, stream>>>(W_c2, Wtc2, 256, 128, 128);
  wtrans_kernel<<<(64*768 + 255)/256, 256, 0, stream>>>(W_lin2, Wtf, 768, 40, 64);
  // h = relu(x @ W_lin1 + b)
  gemm_kernel<4,4,2,2,1><<<dim3(mt, 2), 256, 0, stream>>>(xb, nullptr, nullptr, Wt1, b_lin1, h, N, 512, 512, 256);

  // --- graph preprocessing (overwrites xb slab with padded CSR) ---
  (void)hipMemsetAsync(degblk, 0, (size_t)4*N*4, stream);
  (void)hipMemsetAsync(csr1, 0, (cap1 + cap2)*8, stream);
  hist_kernel<<<(E1 + 255)/256, 256, 0, stream>>>(ei1 + E1, E1, deg1);
  hist_kernel<<<(E2 + 255)/256, 256, 0, stream>>>(ei2 + E2, E2, deg2);
  dis_kernel<<<(N + 255)/256, 256, 0, stream>>>(deg1, deg2, dis1, dis2, N);
  int nch = (N + 1023)/1024;
  scan1_kernel<<<dim3(nch, 2), 1024, 0, stream>>>(deg1, deg2, off1, off2, bsum, N);
  scan2_kernel<<<1, 64, 0, stream>>>(bsum, bbase, nch, off1, off2, N);
  scan3_kernel<<<dim3(nch, 2), 1024, 0, stream>>>(deg1, deg2, off1, off2, bbase, N);
  scatter_kernel<<<(E1 + 255)/256, 256, 0, stream>>>(ei1, E1, off1, cur1, dis1, (int2*)csr1);
  scatter_kernel<<<(E2 + 255)/256, 256, 0, stream>>>(ei2, E2, off2, cur2, dis2, (int2*)csr2);

  // --- layer 1 ---
  gemm_kernel<4,4,2,2,0><<<dim3(mt, 1), 256, 0, stream>>>(h, nullptr, nullptr, Wtc1, nullptr, hw, N, 256, 256, 128);
  conv_kernel<<<dim3(cb, 2), 256, 0, stream>>>(off1, csr1, dis1, off2, csr2, dis2,
                                               (const u32x2*)hw, b_c1, R1, N);
  // --- layer 2 ---
  gemm_kernel<4,4,2,2,0><<<dim3(mt, 1), 256, 0, stream>>>(R1, nullptr, nullptr, Wtc2, nullptr, hw, N, 256, 256, 128);
  conv_kernel<<<dim3(cb, 2), 256, 0, stream>>>(off1, csr1, dis1, off2, csr2, dis2,
                                               (const u32x2*)hw, b_c2, R2, N);
  // --- head: logits = [h|R1|R2] @ W_lin2 + b, fused log_softmax ---
  gemm_kernel<2,4,4,1,2><<<dim3(mt, 1), 256, 0, stream>>>(h, R1, R2, Wtf, b_lin2, d_out, N, 768, 256, 40);
}